// Round 6
// baseline (182.996 us; speedup 1.0000x reference)
//
#include <hip/hip_runtime.h>
#include <math.h>

// ---------------------------------------------------------------------------
// QCNN forward. Inter-kernel state uses layout F (per batch, 20 bits):
//   F0=a0(u0) F1=a1(t0) F2=a2(s0) F3=a3(t1) F4=a12(u3) F5=a16(u4) F6=a14(s3)
//   F7=a18(s4) F8=a4(u1) F9=a8(u2) F10=a6(s1) F11=a10(s2) F12=a5(t2)
//   F13..19 = thi
// pass1: tile=addr bits 0..12 (R3 shape: 512thr/2^13), permuted store into F.
// pass2: tile = F bits {0..7,15..19} (in-place safe; gates rescheduled).
// pool:  contiguous 64KB gather per (b,thi); LDS w[t*1153+s*36+u]
//        (T=1153, S=36: mod-16 residues 1/4 -> bank floor, R3 fix);
//        512-thread LDS fold -> coalesced float4 partial store (no atomics:
//        fine-grained ws atomics write through to HBM — R2 post-mortem).
// finish: fold 128 tiles + layers 2..4 + measure. One block per batch.
// R4 lesson: staging loops were ~2-deep on memory-level parallelism ->
// latency-serialized (21% VALU, 12% HBM). BURST staging: 8 global loads
// into named regs before any LDS write; 16 LDS reads before global stores.
// R5 note: identical source resubmitted — R5 bench died on container infra
// (acquire/profile strain visible in R4 timing), not on this kernel.
// Complex math on <2 x float> ext-vectors -> v_pk_fma_f32.
// ---------------------------------------------------------------------------

typedef float cpx __attribute__((ext_vector_type(2)));

__device__ __forceinline__ cpx mkc(float x, float y) { cpx r; r.x = x; r.y = y; return r; }

__device__ __forceinline__ cpx cmul(cpx a, cpx b) {
  cpx r = a.xx * b;
  return __builtin_elementwise_fma(mkc(-a.y, a.y), b.yx, r);
}
__device__ __forceinline__ cpx cmadd(cpx acc, cpx a, cpx b) {
  acc = __builtin_elementwise_fma(a.xx, b, acc);
  return __builtin_elementwise_fma(mkc(-a.y, a.y), b.yx, acc);
}
// acc += a * conj(b)
__device__ __forceinline__ cpx cmaddc(cpx acc, cpx a, cpx b) {
  acc = __builtin_elementwise_fma(a.xx, mkc(b.x, -b.y), acc);
  return __builtin_elementwise_fma(a.yy, b.yx, acc);
}

__device__ __forceinline__ int pad(int e) { return e + (e >> 4); }
__device__ __forceinline__ int ins(int x, int p) {
  return ((x >> p) << (p + 1)) | (x & ((1 << p) - 1));
}

#define S_STR 36
#define T_STR 1153

__device__ __forceinline__ void gate4(cpx& v0, cpx& v1, cpx& v2, cpx& v3,
                                      const cpx (&U)[16]) {
  cpx n0 = cmul(U[0], v0);  n0 = cmadd(n0, U[1], v1);  n0 = cmadd(n0, U[2], v2);  n0 = cmadd(n0, U[3], v3);
  cpx n1 = cmul(U[4], v0);  n1 = cmadd(n1, U[5], v1);  n1 = cmadd(n1, U[6], v2);  n1 = cmadd(n1, U[7], v3);
  cpx n2 = cmul(U[8], v0);  n2 = cmadd(n2, U[9], v1);  n2 = cmadd(n2, U[10], v2); n2 = cmadd(n2, U[11], v3);
  cpx n3 = cmul(U[12], v0); n3 = cmadd(n3, U[13], v1); n3 = cmadd(n3, U[14], v2); n3 = cmadd(n3, U[15], v3);
  v0 = n0; v1 = n1; v2 = n2; v3 = n3;
}

template <int NG>
__device__ __forceinline__ void gate16n(cpx (&v)[16], const cpx (&U)[16]) {
#pragma unroll
  for (int g = 0; g < 4; g++)
    gate4(v[g * 4 + 0], v[g * 4 + 1], v[g * 4 + 2], v[g * 4 + 3], U);
#pragma unroll
  for (int lo = 0; lo < 4; lo++)
    gate4(v[lo], v[lo + 4], v[lo + 8], v[lo + 12], U);
  if (NG == 3) {
#pragma unroll
    for (int b3 = 0; b3 < 2; b3++)
#pragma unroll
      for (int b0 = 0; b0 < 2; b0++) {
        int j = b3 * 8 + b0;
        gate4(v[j], v[j + 2], v[j + 4], v[j + 6], U);
      }
  }
}

// single 2-qubit gate over padded 2^13 LDS tile (512 thr)
__device__ __forceinline__ void apply_gate_tile13(cpx* t, const cpx (&U)[16],
                                                  int pa, int pb, int tid) {
  int p0 = pa < pb ? pa : pb;
  int p1 = pa < pb ? pb : pa;
  int m0 = (1 << p0) - 1, m1 = (1 << p1) - 1;
  int ia = 1 << pa, ib = 1 << pb;
#pragma unroll
  for (int g = tid; g < 2048; g += 512) {
    int idx = ((g & ~m0) << 1) | (g & m0);
    idx = ((idx & ~m1) << 1) | (idx & m1);
    int e0 = pad(idx), e1 = pad(idx | ib), e2 = pad(idx | ia), e3 = pad(idx | ia | ib);
    cpx v0 = t[e0], v1 = t[e1], v2 = t[e2], v3 = t[e3];
    gate4(v0, v1, v2, v3, U);
    t[e0] = v0; t[e1] = v1; t[e2] = v2; t[e3] = v3;
  }
}

template <int NG>
__device__ __forceinline__ void phase4_f(cpx* t, const cpx (&U)[16],
                                         int q0, int q1, int q2, int q3,
                                         int o0, int o1, int o2, int o3, int tid) {
  int idx = ins(ins(ins(ins(tid, q0), q1), q2), q3);
  cpx v[16];
#pragma unroll
  for (int j = 0; j < 16; j++) {
    int off = ((j & 1) ? o0 : 0) + ((j & 2) ? o1 : 0) + ((j & 4) ? o2 : 0) + ((j & 8) ? o3 : 0);
    v[j] = t[pad(idx + off)];
  }
  gate16n<NG>(v, U);
#pragma unroll
  for (int j = 0; j < 16; j++) {
    int off = ((j & 1) ? o0 : 0) + ((j & 2) ? o1 : 0) + ((j & 4) ? o2 : 0) + ((j & 8) ? o3 : 0);
    t[pad(idx + off)] = v[j];
  }
}

template <int NG>
__device__ __forceinline__ void phase4_pool(cpx* w, const cpx (&U)[16],
                                            int a_lo, int a_hi, int c_lo, int c_hi,
                                            int o0, int o1, int o2, int o3, int tid) {
  int uu = tid & 7, ss = (tid >> 3) & 7, t_lo = tid >> 6;
  int u = ins(ins(uu, a_lo), a_hi);
  int s = ins(ins(ss, c_lo), c_hi);
  int base = t_lo * T_STR + s * S_STR + u;
  cpx v[16];
#pragma unroll
  for (int j = 0; j < 16; j++) {
    int off = ((j & 1) ? o0 : 0) + ((j & 2) ? o1 : 0) + ((j & 4) ? o2 : 0) + ((j & 8) ? o3 : 0);
    v[j] = w[base + off];
  }
  gate16n<NG>(v, U);
#pragma unroll
  for (int j = 0; j < 16; j++) {
    int off = ((j & 1) ? o0 : 0) + ((j & 2) ? o1 : 0) + ((j & 4) ? o2 : 0) + ((j & 8) ? o3 : 0);
    w[base + off] = v[j];
  }
}

__device__ __forceinline__ void pool_p3(cpx* w, const cpx (&U)[16], int tid) {
#pragma unroll
  for (int it = 0; it < 2; it++) {
    int h = tid + it * 512;
    int t_lo = h & 7, ss = (h >> 3) & 15, uu = (h >> 7) & 7;
    int base = t_lo * T_STR + (ss << 1) * S_STR + (uu << 2);
    cpx v[8];
    v[0] = w[base];          v[1] = w[base + 1];
    v[4] = w[base + 2];      v[5] = w[base + 3];
    v[2] = w[base + S_STR];      v[3] = w[base + S_STR + 1];
    v[6] = w[base + S_STR + 2];  v[7] = w[base + S_STR + 3];
    gate4(v[0], v[1], v[2], v[3], U);
    gate4(v[4], v[5], v[6], v[7], U);
    gate4(v[0], v[2], v[4], v[6], U);
    gate4(v[1], v[3], v[5], v[7], U);
    w[base] = v[0];          w[base + 1] = v[1];
    w[base + 2] = v[4];      w[base + 3] = v[5];
    w[base + S_STR] = v[2];      w[base + S_STR + 1] = v[3];
    w[base + S_STR + 2] = v[6];  w[base + S_STR + 3] = v[7];
  }
}

// 16-lane expm(A - A^H) in fp64, width-16 shuffles.
__device__ __forceinline__ cpx expm16(const float* __restrict__ Hre,
                                      const float* __restrict__ Him,
                                      int l, int l16) {
  int r = l16 >> 2, c = l16 & 3;
  double tr = (double)Hre[l * 16 + r * 4 + c] - (double)Hre[l * 16 + c * 4 + r];
  double ti = (double)Him[l * 16 + r * 4 + c] + (double)Him[l * 16 + c * 4 + r];
  double a = sqrt(tr * tr + ti * ti);
  a += __shfl_xor(a, 1, 16);
  a += __shfl_xor(a, 2, 16);
  double nrm = fmax(a, __shfl_xor(a, 4, 16));
  nrm = fmax(nrm, __shfl_xor(nrm, 8, 16));
  int s = 0;
  while (nrm > 0.25 && s < 60) { nrm *= 0.5; s++; }
  double sc = ldexp(1.0, -s);
  tr *= sc; ti *= sc;
  double id = (r == c) ? 1.0 : 0.0;
  double er = id, ei = 0.0, pr = id, pi = 0.0;
  for (int k = 1; k <= 16; k++) {
    double qr = 0.0, qi = 0.0;
#pragma unroll
    for (int m = 0; m < 4; m++) {
      double pmr = __shfl(pr, r * 4 + m, 16);
      double pmi = __shfl(pi, r * 4 + m, 16);
      double tmr = __shfl(tr, m * 4 + c, 16);
      double tmi = __shfl(ti, m * 4 + c, 16);
      qr = fma(pmr, tmr, fma(-pmi, tmi, qr));
      qi = fma(pmr, tmi, fma(pmi, tmr, qi));
    }
    double inv = 1.0 / (double)k;
    pr = qr * inv; pi = qi * inv;
    er += pr; ei += pi;
  }
  for (int it = 0; it < s; it++) {
    double qr = 0.0, qi = 0.0;
#pragma unroll
    for (int m = 0; m < 4; m++) {
      double amr = __shfl(er, r * 4 + m, 16);
      double ami = __shfl(ei, r * 4 + m, 16);
      double bmr = __shfl(er, m * 4 + c, 16);
      double bmi = __shfl(ei, m * 4 + c, 16);
      qr = fma(amr, bmr, fma(-ami, bmi, qr));
      qi = fma(amr, bmi, fma(ami, bmr, qi));
    }
    er = qr; ei = qi;
  }
  return mkc((float)er, (float)ei);
}

// ---------------------------------------------------------------------------
// Kernel B: layer-0 pass 1 (512 blk x 512 thr, 2^13 tile) + expm.
// Burst staging: 8 global loads -> regs -> LDS; expm AFTER ds_writes.
// ---------------------------------------------------------------------------
__global__ __launch_bounds__(512, 4) void l0_pass1(const float* __restrict__ pre,
                                                   const float* __restrict__ pim,
                                                   const float* __restrict__ Hre,
                                                   const float* __restrict__ Him,
                                                   cpx* __restrict__ Umat,
                                                   cpx* __restrict__ state) {
  extern __shared__ cpx tile[];
  __shared__ cpx Ush[16];
  int tid = threadIdx.x;
  int bid = blockIdx.x;
  int b = bid >> 7, hi = bid & 127;   // hi = addr bits 13..19
  size_t base = ((size_t)b << 20) | ((size_t)hi << 13);
  // burst: 8 independent float4 loads
  float4 re[4], im[4];
#pragma unroll
  for (int k = 0; k < 4; k++) {
    int e = (tid + (k << 9)) << 2;
    re[k] = *(const float4*)&pre[base + e];
    im[k] = *(const float4*)&pim[base + e];
  }
#pragma unroll
  for (int k = 0; k < 4; k++) {
    int e = (tid + (k << 9)) << 2;
    int d = pad(e);
    tile[d]     = mkc(re[k].x, im[k].x);
    tile[d + 1] = mkc(re[k].y, im[k].y);
    tile[d + 2] = mkc(re[k].z, im[k].z);
    tile[d + 3] = mkc(re[k].w, im[k].w);
  }
  {
    int wv = tid >> 6, g16 = (tid & 63) >> 4, l16 = tid & 15;
    int layer = (wv == 0) ? g16 : ((wv == 1 && g16 == 0) ? 4 : -1);
    if (layer == 0 || (bid == 0 && layer > 0)) {
      cpx ue = expm16(Hre, Him, layer, l16);
      if (layer == 0) Ush[l16] = ue;
      if (bid == 0) Umat[layer * 16 + l16] = ue;
    }
  }
  __syncthreads();
  cpx U[16];
#pragma unroll
  for (int k = 0; k < 16; k++) U[k] = Ush[k];
  phase4_f<3>(tile, U, 0, 1, 2, 3, 1, 2, 4, 8, tid);            __syncthreads(); // (a1,a0),(a3,a2),(a2,a1)
  phase4_f<3>(tile, U, 4, 5, 6, 7, 16, 32, 64, 128, tid);       __syncthreads(); // (a5,a4),(a7,a6),(a6,a5)
  phase4_f<3>(tile, U, 8, 9, 10, 11, 256, 512, 1024, 2048, tid);__syncthreads(); // (a9,a8),(a11,a10),(a10,a9)
  phase4_f<2>(tile, U, 3, 4, 7, 8, 8, 16, 128, 256, tid);       __syncthreads(); // (a4,a3),(a8,a7)
  // permuted store to F (R3 maps):
  int hifix = ((hi & 1) << 16) | (((hi >> 1) & 1) << 6) | (((hi >> 2) & 1) << 17)
            | (((hi >> 3) & 1) << 5) | (((hi >> 4) & 1) << 18) | (((hi >> 5) & 1) << 7)
            | (((hi >> 6) & 1) << 19);
  size_t dbase = ((size_t)b << 20) | (unsigned)hifix;
  // burst: 16 LDS reads -> regs, then 8 scatter dwordx4 stores
  cpx x[16];
#pragma unroll
  for (int k = 0; k < 4; k++) {
    int src = pad((tid + (k << 9)) << 2);
    x[4 * k + 0] = tile[src];     x[4 * k + 1] = tile[src + 1];
    x[4 * k + 2] = tile[src + 2]; x[4 * k + 3] = tile[src + 3];
  }
#pragma unroll
  for (int k = 0; k < 4; k++) {
    int le = tid + (k << 9);
    int d = ((le & 1) << 2) | (((le >> 1) & 1) << 3) | (((le >> 2) & 1) << 8)
          | (((le >> 3) & 1) << 12) | (((le >> 4) & 1) << 10) | (((le >> 5) & 1) << 13)
          | (((le >> 6) & 1) << 9) | (((le >> 7) & 1) << 14) | (((le >> 8) & 1) << 11)
          | (((le >> 9) & 1) << 15) | (((le >> 10) & 1) << 4);
    float4* dst = (float4*)&state[dbase + d];
    dst[0] = make_float4(x[4 * k].x, x[4 * k].y, x[4 * k + 1].x, x[4 * k + 1].y);
    dst[1] = make_float4(x[4 * k + 2].x, x[4 * k + 2].y, x[4 * k + 3].x, x[4 * k + 3].y);
  }
}

// ---------------------------------------------------------------------------
// Kernel C: layer-0 pass 2 in layout F. Burst staging both directions.
// ---------------------------------------------------------------------------
__global__ __launch_bounds__(512, 4) void l0_pass2(const cpx* __restrict__ Umat,
                                                   cpx* __restrict__ state) {
  extern __shared__ cpx tile[];
  int tid = threadIdx.x;
  int bid = blockIdx.x;
  int b = bid >> 7, mid = bid & 127;
  size_t base = ((size_t)b << 20) | ((size_t)mid << 8);
  cpx U[16];
#pragma unroll
  for (int k = 0; k < 16; k++) U[k] = Umat[k];
  {
    float4 v[8];
#pragma unroll
    for (int k = 0; k < 8; k++) {
      int f = tid + (k << 9);
      int run = f >> 7, idx = f & 127;
      v[k] = *(const float4*)&state[base + ((size_t)run << 15) + ((size_t)idx << 1)];
    }
#pragma unroll
    for (int k = 0; k < 8; k++) {
      int f = tid + (k << 9);
      int d = pad((f >> 7) * 256 + (f & 127) * 2);
      tile[d] = mkc(v[k].x, v[k].y);
      tile[d + 1] = mkc(v[k].z, v[k].w);
    }
  }
  __syncthreads();
  phase4_f<3>(tile, U, 4, 6, 9, 10, 16, 512, 64, 1024, tid);    __syncthreads(); // E1,E2,O2
  phase4_f<3>(tile, U, 5, 7, 11, 12, 32, 2048, 128, 4096, tid); __syncthreads(); // E3,E4,O4
  phase4_f<2>(tile, U, 4, 5, 8, 10, 256, 16, 1024, 32, tid);    __syncthreads(); // O1,O3
  apply_gate_tile13(tile, U, 0, 12, tid);                       __syncthreads(); // W
  {
    cpx y[16];
#pragma unroll
    for (int k = 0; k < 8; k++) {
      int f = tid + (k << 9);
      int d = pad((f >> 7) * 256 + (f & 127) * 2);
      y[2 * k] = tile[d];
      y[2 * k + 1] = tile[d + 1];
    }
#pragma unroll
    for (int k = 0; k < 8; k++) {
      int f = tid + (k << 9);
      int run = f >> 7, idx = f & 127;
      size_t a = base + ((size_t)run << 15) + ((size_t)idx << 1);
      *(float4*)&state[a] = make_float4(y[2 * k].x, y[2 * k].y, y[2 * k + 1].x, y[2 * k + 1].y);
    }
  }
}

// ---------------------------------------------------------------------------
// Kernel D: pool0 + layer1 gates + pool1. Burst gather; non-atomic partials.
// ---------------------------------------------------------------------------
__global__ __launch_bounds__(512, 4) void pool_l1(const cpx* __restrict__ Umat,
                                                  const cpx* __restrict__ state,
                                                  float4* __restrict__ partial) {
  extern __shared__ cpx w[];  // 8*T_STR = 9224 cpx
  int tid = threadIdx.x;
  int bid = blockIdx.x;
  int b = bid >> 7, thi = bid & 127;
  size_t base = ((size_t)b << 20) | ((size_t)thi << 13);
  cpx U[16];
#pragma unroll
  for (int k = 0; k < 16; k++) U[k] = Umat[16 + k];
  {
    float4 v[8];
#pragma unroll
    for (int k = 0; k < 8; k++) {
      int e = (tid + (k << 9)) << 1;
      v[k] = *(const float4*)&state[base + e];
    }
#pragma unroll
    for (int k = 0; k < 8; k++) {
      int e = (tid + (k << 9)) << 1;
      int u = (((e >> 8) & 1) << 1) | (((e >> 9) & 1) << 2) | (((e >> 4) & 1) << 3) | (((e >> 5) & 1) << 4);
      int s = ((e >> 2) & 1) | (((e >> 10) & 1) << 1) | (((e >> 11) & 1) << 2)
            | (((e >> 6) & 1) << 3) | (((e >> 7) & 1) << 4);
      int t = ((e >> 1) & 1) | (((e >> 3) & 1) << 1) | (((e >> 12) & 1) << 2);
      int c = t * T_STR + s * S_STR + u;
      w[c] = mkc(v[k].x, v[k].y);
      w[c + 1] = mkc(v[k].z, v[k].w);
    }
  }
  __syncthreads();
  phase4_pool<3>(w, U, 3, 4, 3, 4, 8, 8 * S_STR, 16, 16 * S_STR, tid); __syncthreads(); // {7,6},{9,8},{8,7}
  phase4_pool<3>(w, U, 1, 2, 1, 2, 2, 2 * S_STR, 4, 4 * S_STR, tid);   __syncthreads(); // {3,2},{5,4},{4,3}
  pool_p3(w, U, tid);                                                  __syncthreads(); // {1,0},{2,1}
  phase4_pool<2>(w, U, 0, 3, 2, 4, 4 * S_STR, 8, 16 * S_STR, 1, tid);  __syncthreads(); // {6,5},{0,9}
  int wv = tid >> 6, lane = tid & 63;
  int u0 = (lane >> 3) << 2, v0 = (lane & 7) << 2;
  cpx acc[4][4];
#pragma unroll
  for (int i = 0; i < 4; i++)
#pragma unroll
    for (int j = 0; j < 4; j++) acc[i][j] = mkc(0.f, 0.f);
  {
    int tb = wv * T_STR;
#pragma unroll 4
    for (int s = 0; s < 32; s++) {
      int row = tb + s * S_STR;
      cpx x[4], y[4];
#pragma unroll
      for (int i = 0; i < 4; i++) { x[i] = w[row + u0 + i]; y[i] = w[row + v0 + i]; }
#pragma unroll
      for (int i = 0; i < 4; i++)
#pragma unroll
        for (int j = 0; j < 4; j++) acc[i][j] = cmaddc(acc[i][j], x[i], y[j]);
    }
  }
  __syncthreads();  // w dead; reuse for cross-wave reduce
#pragma unroll
  for (int i = 0; i < 4; i++)
#pragma unroll
    for (int j = 0; j < 4; j++)
      w[wv * 1024 + (u0 + i) * 32 + (v0 + j)] = acc[i][j];
  __syncthreads();
  {
    cpx s0 = mkc(0.f, 0.f), s1 = mkc(0.f, 0.f);
#pragma unroll
    for (int k = 0; k < 8; k++) {
      s0 += w[k * 1024 + 2 * tid];
      s1 += w[k * 1024 + 2 * tid + 1];
    }
    partial[((size_t)bid << 9) | tid] = make_float4(s0.x, s0.y, s1.x, s1.y);
  }
}

// ---------------------------------------------------------------------------
// Kernel F: fold 128 tiles + layers 2..4 (32x32 -> 2x2 dm) + measure.
// ---------------------------------------------------------------------------
__global__ __launch_bounds__(256) void finish(const cpx* __restrict__ Umat,
                                              const float4* __restrict__ accv,
                                              float* __restrict__ out) {
  __shared__ cpx rho[1024];
  __shared__ cpx r3s[64];
  __shared__ cpx r4s[16];
  int tid = threadIdx.x;
  int b = blockIdx.x;
  float4* rf = (float4*)rho;
  for (int f = tid; f < 512; f += 256) {
    float4 acc = make_float4(0.f, 0.f, 0.f, 0.f);
#pragma unroll 8
    for (int h = 0; h < 128; h++) {
      float4 v = accv[(size_t)(b * 128 + h) * 512 + f];
      acc.x += v.x; acc.y += v.y; acc.z += v.z; acc.w += v.w;
    }
    rf[f] = acc;
  }
  __syncthreads();

  cpx U[16], Uc[16];
#pragma unroll
  for (int k = 0; k < 16; k++) { U[k] = Umat[32 + k]; Uc[k] = mkc(U[k].x, -U[k].y); }
  const int gl2[4][2] = {{4,3},{2,1},{3,2},{1,0}};
#pragma unroll
  for (int gi = 0; gi < 4; gi++) {
    int pa = gl2[gi][0], pb = gl2[gi][1];
    int p0 = pa < pb ? pa : pb, p1 = pa < pb ? pb : pa;
    int m0 = (1 << p0) - 1, m1 = (1 << p1) - 1;
    int ia = 1 << pa, ib = 1 << pb;
    {
      int j = tid >> 3, g = tid & 7;
      int idx = ((g & ~m0) << 1) | (g & m0);
      idx = ((idx & ~m1) << 1) | (idx & m1);
      cpx v0 = rho[idx * 32 + j], v1 = rho[(idx | ib) * 32 + j];
      cpx v2 = rho[(idx | ia) * 32 + j], v3 = rho[(idx | ia | ib) * 32 + j];
      gate4(v0, v1, v2, v3, U);
      rho[idx * 32 + j] = v0; rho[(idx | ib) * 32 + j] = v1;
      rho[(idx | ia) * 32 + j] = v2; rho[(idx | ia | ib) * 32 + j] = v3;
    }
    __syncthreads();
    {
      int i = tid >> 3, g = tid & 7;
      int idx = ((g & ~m0) << 1) | (g & m0);
      idx = ((idx & ~m1) << 1) | (idx & m1);
      cpx v0 = rho[i * 32 + idx], v1 = rho[i * 32 + (idx | ib)];
      cpx v2 = rho[i * 32 + (idx | ia)], v3 = rho[i * 32 + (idx | ia | ib)];
      gate4(v0, v1, v2, v3, Uc);
      rho[i * 32 + idx] = v0; rho[i * 32 + (idx | ib)] = v1;
      rho[i * 32 + (idx | ia)] = v2; rho[i * 32 + (idx | ia | ib)] = v3;
    }
    __syncthreads();
  }
  if (tid < 64) {
    int u = tid >> 3, v = tid & 7;
    cpx acc = mkc(0.f, 0.f);
#pragma unroll
    for (int s = 0; s < 4; s++) {
      int iu = ((s >> 1) << 4) | ((u >> 2) << 3) | ((s & 1) << 2) | (((u >> 1) & 1) << 1) | (u & 1);
      int iv = ((s >> 1) << 4) | ((v >> 2) << 3) | ((s & 1) << 2) | (((v >> 1) & 1) << 1) | (v & 1);
      cpx x = rho[iu * 32 + iv];
      acc.x += x.x; acc.y += x.y;
    }
    r3s[u * 8 + v] = acc;
  }
  __syncthreads();

#pragma unroll
  for (int k = 0; k < 16; k++) { U[k] = Umat[48 + k]; Uc[k] = mkc(U[k].x, -U[k].y); }
  const int gl3[2][2] = {{2,1},{1,0}};
#pragma unroll
  for (int gi = 0; gi < 2; gi++) {
    int pa = gl3[gi][0], pb = gl3[gi][1];
    int p0 = pa < pb ? pa : pb, p1 = pa < pb ? pb : pa;
    int m0 = (1 << p0) - 1, m1 = (1 << p1) - 1;
    int ia = 1 << pa, ib = 1 << pb;
    if (tid < 16) {
      int j = tid >> 1, g = tid & 1;
      int idx = ((g & ~m0) << 1) | (g & m0);
      idx = ((idx & ~m1) << 1) | (idx & m1);
      cpx v0 = r3s[idx * 8 + j], v1 = r3s[(idx | ib) * 8 + j];
      cpx v2 = r3s[(idx | ia) * 8 + j], v3 = r3s[(idx | ia | ib) * 8 + j];
      gate4(v0, v1, v2, v3, U);
      r3s[idx * 8 + j] = v0; r3s[(idx | ib) * 8 + j] = v1;
      r3s[(idx | ia) * 8 + j] = v2; r3s[(idx | ia | ib) * 8 + j] = v3;
    }
    __syncthreads();
    if (tid < 16) {
      int i = tid >> 1, g = tid & 1;
      int idx = ((g & ~m0) << 1) | (g & m0);
      idx = ((idx & ~m1) << 1) | (idx & m1);
      cpx v0 = r3s[i * 8 + idx], v1 = r3s[i * 8 + (idx | ib)];
      cpx v2 = r3s[i * 8 + (idx | ia)], v3 = r3s[i * 8 + (idx | ia | ib)];
      gate4(v0, v1, v2, v3, Uc);
      r3s[i * 8 + idx] = v0; r3s[i * 8 + (idx | ib)] = v1;
      r3s[i * 8 + (idx | ia)] = v2; r3s[i * 8 + (idx | ia | ib)] = v3;
    }
    __syncthreads();
  }
  if (tid < 16) {
    int u = tid >> 2, v = tid & 3;
    cpx acc = mkc(0.f, 0.f);
#pragma unroll
    for (int s = 0; s < 2; s++) {
      cpx x = r3s[((s << 2) | u) * 8 + ((s << 2) | v)];
      acc.x += x.x; acc.y += x.y;
    }
    r4s[u * 4 + v] = acc;
  }
  __syncthreads();

#pragma unroll
  for (int k = 0; k < 16; k++) { U[k] = Umat[64 + k]; Uc[k] = mkc(U[k].x, -U[k].y); }
  if (tid < 4) {
    int j = tid;
    cpx v0 = r4s[0 * 4 + j], v1 = r4s[1 * 4 + j], v2 = r4s[2 * 4 + j], v3 = r4s[3 * 4 + j];
    gate4(v0, v1, v2, v3, U);
    r4s[0 * 4 + j] = v0; r4s[1 * 4 + j] = v1; r4s[2 * 4 + j] = v2; r4s[3 * 4 + j] = v3;
  }
  __syncthreads();
  if (tid < 4) {
    int i = tid;
    cpx v0 = r4s[i * 4 + 0], v1 = r4s[i * 4 + 1], v2 = r4s[i * 4 + 2], v3 = r4s[i * 4 + 3];
    gate4(v0, v1, v2, v3, Uc);
    r4s[i * 4 + 0] = v0; r4s[i * 4 + 1] = v1; r4s[i * 4 + 2] = v2; r4s[i * 4 + 3] = v3;
  }
  __syncthreads();
  if (tid == 0) out[b] = r4s[0].x + r4s[10].x;
}

// ---------------------------------------------------------------------------
extern "C" void kernel_launch(void* const* d_in, const int* in_sizes, int n_in,
                              void* d_out, int out_size, void* d_ws, size_t ws_size,
                              hipStream_t stream) {
  const float* psi_re = (const float*)d_in[0];
  const float* psi_im = (const float*)d_in[1];
  const float* H_re = (const float*)d_in[2];
  const float* H_im = (const float*)d_in[3];
  float* out = (float*)d_out;

  char* ws = (char*)d_ws;
  cpx* Umat = (cpx*)ws;                                       // 80 cpx
  cpx* state = (cpx*)(ws + 4096);                             // 32 MB (layout F)
  float4* partial = (float4*)(ws + 4096 + ((size_t)1 << 25)); // 4 MB

  const size_t LDS_L0 = 8704 * sizeof(cpx);          // padded 8192 = 69632 B
  const size_t LDS_POOL = 8 * T_STR * sizeof(cpx);   // 9224 cpx = 73792 B

  hipLaunchKernelGGL(l0_pass1, dim3(512), dim3(512), LDS_L0, stream,
                     psi_re, psi_im, H_re, H_im, Umat, state);
  hipLaunchKernelGGL(l0_pass2, dim3(512), dim3(512), LDS_L0, stream,
                     (const cpx*)Umat, state);
  hipLaunchKernelGGL(pool_l1, dim3(512), dim3(512), LDS_POOL, stream,
                     (const cpx*)Umat, (const cpx*)state, partial);
  hipLaunchKernelGGL(finish, dim3(4), dim3(256), 0, stream,
                     (const cpx*)Umat, (const float4*)partial, out);
}

// Round 7
// 175.887 us; speedup vs baseline: 1.0404x; 1.0404x over previous
//
#include <hip/hip_runtime.h>
#include <math.h>

// ---------------------------------------------------------------------------
// QCNN forward. Inter-kernel state uses layout F (per batch, 20 bits):
//   F0=a0(u0) F1=a1(t0) F2=a2(s0) F3=a3(t1) F4=a12(u3) F5=a16(u4) F6=a14(s3)
//   F7=a18(s4) F8=a4(u1) F9=a8(u2) F10=a6(s1) F11=a10(s2) F12=a5(t2)
//   F13..19 = thi
// R6 post-mortem: chain is LATENCY-bound (R4: VALU 21%, HBM 12%, occ 38%).
// LDS (69.6KB) caps 2 blocks/CU; at 512thr that's 16 waves/CU. This round:
// pass1/pass2 -> 1024 threads (32 waves/CU) with 8-cpx phases (2 gates each;
// same commuting-gate DAG, bitwise-identical results) and U in SGPRs
// (expm hoisted to a tiny compute_U kernel; uniform global loads go scalar —
// pool's VGPR=36 proves it). Target VGPR<=64 for 8 waves/SIMD.
// pool: R6 512-thr version (T=1153/S=36 bank-floor strides, burst gather,
// non-atomic partials — ws atomics write through to HBM, R2). finish: R6.
// Complex math on <2 x float> ext-vectors -> v_pk_fma_f32.
// ---------------------------------------------------------------------------

typedef float cpx __attribute__((ext_vector_type(2)));

__device__ __forceinline__ cpx mkc(float x, float y) { cpx r; r.x = x; r.y = y; return r; }

__device__ __forceinline__ cpx cmul(cpx a, cpx b) {
  cpx r = a.xx * b;
  return __builtin_elementwise_fma(mkc(-a.y, a.y), b.yx, r);
}
__device__ __forceinline__ cpx cmadd(cpx acc, cpx a, cpx b) {
  acc = __builtin_elementwise_fma(a.xx, b, acc);
  return __builtin_elementwise_fma(mkc(-a.y, a.y), b.yx, acc);
}
// acc += a * conj(b)
__device__ __forceinline__ cpx cmaddc(cpx acc, cpx a, cpx b) {
  acc = __builtin_elementwise_fma(a.xx, mkc(b.x, -b.y), acc);
  return __builtin_elementwise_fma(a.yy, b.yx, acc);
}

__device__ __forceinline__ int pad(int e) { return e + (e >> 4); }
__device__ __forceinline__ int ins(int x, int p) {
  return ((x >> p) << (p + 1)) | (x & ((1 << p) - 1));
}

#define S_STR 36
#define T_STR 1153

__device__ __forceinline__ void gate4(cpx& v0, cpx& v1, cpx& v2, cpx& v3,
                                      const cpx (&U)[16]) {
  cpx n0 = cmul(U[0], v0);  n0 = cmadd(n0, U[1], v1);  n0 = cmadd(n0, U[2], v2);  n0 = cmadd(n0, U[3], v3);
  cpx n1 = cmul(U[4], v0);  n1 = cmadd(n1, U[5], v1);  n1 = cmadd(n1, U[6], v2);  n1 = cmadd(n1, U[7], v3);
  cpx n2 = cmul(U[8], v0);  n2 = cmadd(n2, U[9], v1);  n2 = cmadd(n2, U[10], v2); n2 = cmadd(n2, U[11], v3);
  cpx n3 = cmul(U[12], v0); n3 = cmadd(n3, U[13], v1); n3 = cmadd(n3, U[14], v2); n3 = cmadd(n3, U[15], v3);
  v0 = n0; v1 = n1; v2 = n2; v3 = n3;
}

template <int NG>
__device__ __forceinline__ void gate16n(cpx (&v)[16], const cpx (&U)[16]) {
#pragma unroll
  for (int g = 0; g < 4; g++)
    gate4(v[g * 4 + 0], v[g * 4 + 1], v[g * 4 + 2], v[g * 4 + 3], U);
#pragma unroll
  for (int lo = 0; lo < 4; lo++)
    gate4(v[lo], v[lo + 4], v[lo + 8], v[lo + 12], U);
  if (NG == 3) {
#pragma unroll
    for (int b3 = 0; b3 < 2; b3++)
#pragma unroll
      for (int b0 = 0; b0 < 2; b0++) {
        int j = b3 * 8 + b0;
        gate4(v[j], v[j + 2], v[j + 4], v[j + 6], U);
      }
  }
}

// single 2-qubit gate (hi bit pa, lo bit pb) over padded 2^13 tile, 1024 thr
__device__ __forceinline__ void apply_gate_2it(cpx* t, const cpx (&U)[16],
                                               int pa, int pb, int tid) {
  int p0 = pa < pb ? pa : pb;
  int p1 = pa < pb ? pb : pa;
  int m0 = (1 << p0) - 1, m1 = (1 << p1) - 1;
  int ia = 1 << pa, ib = 1 << pb;
#pragma unroll
  for (int g = tid; g < 2048; g += 1024) {
    int idx = ((g & ~m0) << 1) | (g & m0);
    idx = ((idx & ~m1) << 1) | (idx & m1);
    int e0 = pad(idx), e1 = pad(idx | ib), e2 = pad(idx | ia), e3 = pad(idx | ia | ib);
    cpx v0 = t[e0], v1 = t[e1], v2 = t[e2], v3 = t[e3];
    gate4(v0, v1, v2, v3, U);
    t[e0] = v0; t[e1] = v1; t[e2] = v2; t[e3] = v3;
  }
}

// 8-cpx register phase for 1024 threads over padded 2^13 tile.
// q0<q1<q2 sorted bits; gates: EVEN (o2,o1) first, then ODD (o1,o0).
__device__ __forceinline__ void phase3_eo(cpx* t, const cpx (&U)[16],
                                          int q0, int q1, int q2,
                                          int o0, int o1, int o2, int tid) {
  int idx = ins(ins(ins(tid, q0), q1), q2);
  cpx v[8];
#pragma unroll
  for (int j = 0; j < 8; j++) {
    int off = ((j & 1) ? o0 : 0) + ((j & 2) ? o1 : 0) + ((j & 4) ? o2 : 0);
    v[j] = t[pad(idx + off)];
  }
  gate4(v[0], v[2], v[4], v[6], U);  // (o2,o1), o0=0
  gate4(v[1], v[3], v[5], v[7], U);  // (o2,o1), o0=1
  gate4(v[0], v[1], v[2], v[3], U);  // (o1,o0), o2=0
  gate4(v[4], v[5], v[6], v[7], U);  // (o1,o0), o2=1
#pragma unroll
  for (int j = 0; j < 8; j++) {
    int off = ((j & 1) ? o0 : 0) + ((j & 2) ? o1 : 0) + ((j & 4) ? o2 : 0);
    t[pad(idx + off)] = v[j];
  }
}

// pool register phase (stride-S_STR LDS), 512 threads
template <int NG>
__device__ __forceinline__ void phase4_pool(cpx* w, const cpx (&U)[16],
                                            int a_lo, int a_hi, int c_lo, int c_hi,
                                            int o0, int o1, int o2, int o3, int tid) {
  int uu = tid & 7, ss = (tid >> 3) & 7, t_lo = tid >> 6;
  int u = ins(ins(uu, a_lo), a_hi);
  int s = ins(ins(ss, c_lo), c_hi);
  int base = t_lo * T_STR + s * S_STR + u;
  cpx v[16];
#pragma unroll
  for (int j = 0; j < 16; j++) {
    int off = ((j & 1) ? o0 : 0) + ((j & 2) ? o1 : 0) + ((j & 4) ? o2 : 0) + ((j & 8) ? o3 : 0);
    v[j] = w[base + off];
  }
  gate16n<NG>(v, U);
#pragma unroll
  for (int j = 0; j < 16; j++) {
    int off = ((j & 1) ? o0 : 0) + ((j & 2) ? o1 : 0) + ((j & 4) ? o2 : 0) + ((j & 8) ? o3 : 0);
    w[base + off] = v[j];
  }
}

__device__ __forceinline__ void pool_p3(cpx* w, const cpx (&U)[16], int tid) {
#pragma unroll
  for (int it = 0; it < 2; it++) {
    int h = tid + it * 512;
    int t_lo = h & 7, ss = (h >> 3) & 15, uu = (h >> 7) & 7;
    int base = t_lo * T_STR + (ss << 1) * S_STR + (uu << 2);
    cpx v[8];
    v[0] = w[base];          v[1] = w[base + 1];
    v[4] = w[base + 2];      v[5] = w[base + 3];
    v[2] = w[base + S_STR];      v[3] = w[base + S_STR + 1];
    v[6] = w[base + S_STR + 2];  v[7] = w[base + S_STR + 3];
    gate4(v[0], v[1], v[2], v[3], U);
    gate4(v[4], v[5], v[6], v[7], U);
    gate4(v[0], v[2], v[4], v[6], U);
    gate4(v[1], v[3], v[5], v[7], U);
    w[base] = v[0];          w[base + 1] = v[1];
    w[base + 2] = v[4];      w[base + 3] = v[5];
    w[base + S_STR] = v[2];      w[base + S_STR + 1] = v[3];
    w[base + S_STR + 2] = v[6];  w[base + S_STR + 3] = v[7];
  }
}

// 16-lane expm(A - A^H) in fp64, width-16 shuffles.
__device__ __forceinline__ cpx expm16(const float* __restrict__ Hre,
                                      const float* __restrict__ Him,
                                      int l, int l16) {
  int r = l16 >> 2, c = l16 & 3;
  double tr = (double)Hre[l * 16 + r * 4 + c] - (double)Hre[l * 16 + c * 4 + r];
  double ti = (double)Him[l * 16 + r * 4 + c] + (double)Him[l * 16 + c * 4 + r];
  double a = sqrt(tr * tr + ti * ti);
  a += __shfl_xor(a, 1, 16);
  a += __shfl_xor(a, 2, 16);
  double nrm = fmax(a, __shfl_xor(a, 4, 16));
  nrm = fmax(nrm, __shfl_xor(nrm, 8, 16));
  int s = 0;
  while (nrm > 0.25 && s < 60) { nrm *= 0.5; s++; }
  double sc = ldexp(1.0, -s);
  tr *= sc; ti *= sc;
  double id = (r == c) ? 1.0 : 0.0;
  double er = id, ei = 0.0, pr = id, pi = 0.0;
  for (int k = 1; k <= 16; k++) {
    double qr = 0.0, qi = 0.0;
#pragma unroll
    for (int m = 0; m < 4; m++) {
      double pmr = __shfl(pr, r * 4 + m, 16);
      double pmi = __shfl(pi, r * 4 + m, 16);
      double tmr = __shfl(tr, m * 4 + c, 16);
      double tmi = __shfl(ti, m * 4 + c, 16);
      qr = fma(pmr, tmr, fma(-pmi, tmi, qr));
      qi = fma(pmr, tmi, fma(pmi, tmr, qi));
    }
    double inv = 1.0 / (double)k;
    pr = qr * inv; pi = qi * inv;
    er += pr; ei += pi;
  }
  for (int it = 0; it < s; it++) {
    double qr = 0.0, qi = 0.0;
#pragma unroll
    for (int m = 0; m < 4; m++) {
      double amr = __shfl(er, r * 4 + m, 16);
      double ami = __shfl(ei, r * 4 + m, 16);
      double bmr = __shfl(er, m * 4 + c, 16);
      double bmi = __shfl(ei, m * 4 + c, 16);
      qr = fma(amr, bmr, fma(-ami, bmi, qr));
      qi = fma(amr, bmi, fma(ami, bmr, qi));
    }
    er = qr; ei = qi;
  }
  return mkc((float)er, (float)ei);
}

// ---------------------------------------------------------------------------
// Kernel A: compute all 5 layer unitaries into Umat. 1 block, 128 threads.
// ---------------------------------------------------------------------------
__global__ __launch_bounds__(128) void compute_U(const float* __restrict__ Hre,
                                                 const float* __restrict__ Him,
                                                 cpx* __restrict__ Umat) {
  int tid = threadIdx.x;
  if (tid < 80) {
    int layer = tid >> 4, l16 = tid & 15;
    Umat[layer * 16 + l16] = expm16(Hre, Him, layer, l16);
  }
}

// ---------------------------------------------------------------------------
// Kernel B: layer-0 pass 1. 512 blk x 1024 thr, 2^13 tile, 32 waves/CU.
// Gate order (valid topo order of the commuting DAG — bitwise identical):
// (1,0); (3,2),(2,1); (5,4),(4,3); (7,6),(6,5); (9,8),(8,7); (11,10),(10,9).
// ---------------------------------------------------------------------------
__global__ __launch_bounds__(1024, 8) void l0_pass1(const float* __restrict__ pre,
                                                    const float* __restrict__ pim,
                                                    const cpx* __restrict__ Umat,
                                                    cpx* __restrict__ state) {
  extern __shared__ cpx tile[];
  int tid = threadIdx.x;
  int bid = blockIdx.x;
  int b = bid >> 7, hi = bid & 127;   // hi = addr bits 13..19
  size_t base = ((size_t)b << 20) | ((size_t)hi << 13);
  // burst: 4 independent float4 loads (8 cpx/thread)
  float4 re[2], im[2];
#pragma unroll
  for (int k = 0; k < 2; k++) {
    int e = (tid + (k << 10)) << 2;
    re[k] = *(const float4*)&pre[base + e];
    im[k] = *(const float4*)&pim[base + e];
  }
#pragma unroll
  for (int k = 0; k < 2; k++) {
    int e = (tid + (k << 10)) << 2;
    int d = pad(e);
    tile[d]     = mkc(re[k].x, im[k].x);
    tile[d + 1] = mkc(re[k].y, im[k].y);
    tile[d + 2] = mkc(re[k].z, im[k].z);
    tile[d + 3] = mkc(re[k].w, im[k].w);
  }
  cpx U[16];  // uniform global loads -> SGPRs
#pragma unroll
  for (int k = 0; k < 16; k++) U[k] = Umat[k];
  __syncthreads();
  apply_gate_2it(tile, U, 1, 0, tid);                 __syncthreads(); // (a1,a0)
  phase3_eo(tile, U, 1, 2, 3, 2, 4, 8, tid);          __syncthreads(); // (a3,a2),(a2,a1)
  phase3_eo(tile, U, 3, 4, 5, 8, 16, 32, tid);        __syncthreads(); // (a5,a4),(a4,a3)
  phase3_eo(tile, U, 5, 6, 7, 32, 64, 128, tid);      __syncthreads(); // (a7,a6),(a6,a5)
  phase3_eo(tile, U, 7, 8, 9, 128, 256, 512, tid);    __syncthreads(); // (a9,a8),(a8,a7)
  phase3_eo(tile, U, 9, 10, 11, 512, 1024, 2048, tid);__syncthreads(); // (a11,a10),(a10,a9)
  // permuted store to F (R3-verified maps)
  int hifix = ((hi & 1) << 16) | (((hi >> 1) & 1) << 6) | (((hi >> 2) & 1) << 17)
            | (((hi >> 3) & 1) << 5) | (((hi >> 4) & 1) << 18) | (((hi >> 5) & 1) << 7)
            | (((hi >> 6) & 1) << 19);
  size_t dbase = ((size_t)b << 20) | (unsigned)hifix;
  cpx x[8];
#pragma unroll
  for (int k = 0; k < 2; k++) {
    int src = pad((tid + (k << 10)) << 2);
    x[4 * k + 0] = tile[src];     x[4 * k + 1] = tile[src + 1];
    x[4 * k + 2] = tile[src + 2]; x[4 * k + 3] = tile[src + 3];
  }
#pragma unroll
  for (int k = 0; k < 2; k++) {
    int le = tid + (k << 10);
    int d = ((le & 1) << 2) | (((le >> 1) & 1) << 3) | (((le >> 2) & 1) << 8)
          | (((le >> 3) & 1) << 12) | (((le >> 4) & 1) << 10) | (((le >> 5) & 1) << 13)
          | (((le >> 6) & 1) << 9) | (((le >> 7) & 1) << 14) | (((le >> 8) & 1) << 11)
          | (((le >> 9) & 1) << 15) | (((le >> 10) & 1) << 4);
    float4* dst = (float4*)&state[dbase + d];
    dst[0] = make_float4(x[4 * k].x, x[4 * k].y, x[4 * k + 1].x, x[4 * k + 1].y);
    dst[1] = make_float4(x[4 * k + 2].x, x[4 * k + 2].y, x[4 * k + 3].x, x[4 * k + 3].y);
  }
}

// ---------------------------------------------------------------------------
// Kernel C: layer-0 pass 2 in layout F. 512 blk x 1024 thr.
// Gates (local bits): E1=(9,4),O1=(4,8); E2=(10,6),O2=(6,9); E3=(11,5),
// O3=(5,10); E4=(12,7),O4=(7,11); W=(0,12). Valid topo order (odds disjoint).
// ---------------------------------------------------------------------------
__global__ __launch_bounds__(1024, 8) void l0_pass2(const cpx* __restrict__ Umat,
                                                    cpx* __restrict__ state) {
  extern __shared__ cpx tile[];
  int tid = threadIdx.x;
  int bid = blockIdx.x;
  int b = bid >> 7, mid = bid & 127;
  size_t base = ((size_t)b << 20) | ((size_t)mid << 8);
  cpx U[16];
#pragma unroll
  for (int k = 0; k < 16; k++) U[k] = Umat[k];
  {
    float4 v[4];
#pragma unroll
    for (int k = 0; k < 4; k++) {
      int f = tid + (k << 10);
      int run = f >> 7, idx = f & 127;
      v[k] = *(const float4*)&state[base + ((size_t)run << 15) + ((size_t)idx << 1)];
    }
#pragma unroll
    for (int k = 0; k < 4; k++) {
      int f = tid + (k << 10);
      int d = pad((f >> 7) * 256 + (f & 127) * 2);
      tile[d] = mkc(v[k].x, v[k].y);
      tile[d + 1] = mkc(v[k].z, v[k].w);
    }
  }
  __syncthreads();
  phase3_eo(tile, U, 4, 8, 9, 256, 16, 512, tid);     __syncthreads(); // E1,O1
  phase3_eo(tile, U, 6, 9, 10, 512, 64, 1024, tid);   __syncthreads(); // E2,O2
  phase3_eo(tile, U, 5, 10, 11, 1024, 32, 2048, tid); __syncthreads(); // E3,O3
  phase3_eo(tile, U, 7, 11, 12, 2048, 128, 4096, tid);__syncthreads(); // E4,O4
  apply_gate_2it(tile, U, 0, 12, tid);                __syncthreads(); // W
  {
    cpx y[8];
#pragma unroll
    for (int k = 0; k < 4; k++) {
      int f = tid + (k << 10);
      int d = pad((f >> 7) * 256 + (f & 127) * 2);
      y[2 * k] = tile[d];
      y[2 * k + 1] = tile[d + 1];
    }
#pragma unroll
    for (int k = 0; k < 4; k++) {
      int f = tid + (k << 10);
      int run = f >> 7, idx = f & 127;
      size_t a = base + ((size_t)run << 15) + ((size_t)idx << 1);
      *(float4*)&state[a] = make_float4(y[2 * k].x, y[2 * k].y, y[2 * k + 1].x, y[2 * k + 1].y);
    }
  }
}

// ---------------------------------------------------------------------------
// Kernel D: pool0 + layer1 gates + pool1 (R6 known-good, 512 thr).
// ---------------------------------------------------------------------------
__global__ __launch_bounds__(512, 4) void pool_l1(const cpx* __restrict__ Umat,
                                                  const cpx* __restrict__ state,
                                                  float4* __restrict__ partial) {
  extern __shared__ cpx w[];  // 8*T_STR = 9224 cpx
  int tid = threadIdx.x;
  int bid = blockIdx.x;
  int b = bid >> 7, thi = bid & 127;
  size_t base = ((size_t)b << 20) | ((size_t)thi << 13);
  cpx U[16];
#pragma unroll
  for (int k = 0; k < 16; k++) U[k] = Umat[16 + k];
  {
    float4 v[8];
#pragma unroll
    for (int k = 0; k < 8; k++) {
      int e = (tid + (k << 9)) << 1;
      v[k] = *(const float4*)&state[base + e];
    }
#pragma unroll
    for (int k = 0; k < 8; k++) {
      int e = (tid + (k << 9)) << 1;
      int u = (((e >> 8) & 1) << 1) | (((e >> 9) & 1) << 2) | (((e >> 4) & 1) << 3) | (((e >> 5) & 1) << 4);
      int s = ((e >> 2) & 1) | (((e >> 10) & 1) << 1) | (((e >> 11) & 1) << 2)
            | (((e >> 6) & 1) << 3) | (((e >> 7) & 1) << 4);
      int t = ((e >> 1) & 1) | (((e >> 3) & 1) << 1) | (((e >> 12) & 1) << 2);
      int c = t * T_STR + s * S_STR + u;
      w[c] = mkc(v[k].x, v[k].y);
      w[c + 1] = mkc(v[k].z, v[k].w);
    }
  }
  __syncthreads();
  phase4_pool<3>(w, U, 3, 4, 3, 4, 8, 8 * S_STR, 16, 16 * S_STR, tid); __syncthreads(); // {7,6},{9,8},{8,7}
  phase4_pool<3>(w, U, 1, 2, 1, 2, 2, 2 * S_STR, 4, 4 * S_STR, tid);   __syncthreads(); // {3,2},{5,4},{4,3}
  pool_p3(w, U, tid);                                                  __syncthreads(); // {1,0},{2,1}
  phase4_pool<2>(w, U, 0, 3, 2, 4, 4 * S_STR, 8, 16 * S_STR, 1, tid);  __syncthreads(); // {6,5},{0,9}
  int wv = tid >> 6, lane = tid & 63;
  int u0 = (lane >> 3) << 2, v0 = (lane & 7) << 2;
  cpx acc[4][4];
#pragma unroll
  for (int i = 0; i < 4; i++)
#pragma unroll
    for (int j = 0; j < 4; j++) acc[i][j] = mkc(0.f, 0.f);
  {
    int tb = wv * T_STR;
#pragma unroll 4
    for (int s = 0; s < 32; s++) {
      int row = tb + s * S_STR;
      cpx x[4], y[4];
#pragma unroll
      for (int i = 0; i < 4; i++) { x[i] = w[row + u0 + i]; y[i] = w[row + v0 + i]; }
#pragma unroll
      for (int i = 0; i < 4; i++)
#pragma unroll
        for (int j = 0; j < 4; j++) acc[i][j] = cmaddc(acc[i][j], x[i], y[j]);
    }
  }
  __syncthreads();  // w dead; reuse for cross-wave reduce
#pragma unroll
  for (int i = 0; i < 4; i++)
#pragma unroll
    for (int j = 0; j < 4; j++)
      w[wv * 1024 + (u0 + i) * 32 + (v0 + j)] = acc[i][j];
  __syncthreads();
  {
    cpx s0 = mkc(0.f, 0.f), s1 = mkc(0.f, 0.f);
#pragma unroll
    for (int k = 0; k < 8; k++) {
      s0 += w[k * 1024 + 2 * tid];
      s1 += w[k * 1024 + 2 * tid + 1];
    }
    partial[((size_t)bid << 9) | tid] = make_float4(s0.x, s0.y, s1.x, s1.y);
  }
}

// ---------------------------------------------------------------------------
// Kernel F: fold 128 tiles + layers 2..4 (32x32 -> 2x2 dm) + measure.
// ---------------------------------------------------------------------------
__global__ __launch_bounds__(256) void finish(const cpx* __restrict__ Umat,
                                              const float4* __restrict__ accv,
                                              float* __restrict__ out) {
  __shared__ cpx rho[1024];
  __shared__ cpx r3s[64];
  __shared__ cpx r4s[16];
  int tid = threadIdx.x;
  int b = blockIdx.x;
  float4* rf = (float4*)rho;
  for (int f = tid; f < 512; f += 256) {
    float4 acc = make_float4(0.f, 0.f, 0.f, 0.f);
#pragma unroll 8
    for (int h = 0; h < 128; h++) {
      float4 v = accv[(size_t)(b * 128 + h) * 512 + f];
      acc.x += v.x; acc.y += v.y; acc.z += v.z; acc.w += v.w;
    }
    rf[f] = acc;
  }
  __syncthreads();

  cpx U[16], Uc[16];
#pragma unroll
  for (int k = 0; k < 16; k++) { U[k] = Umat[32 + k]; Uc[k] = mkc(U[k].x, -U[k].y); }
  const int gl2[4][2] = {{4,3},{2,1},{3,2},{1,0}};
#pragma unroll
  for (int gi = 0; gi < 4; gi++) {
    int pa = gl2[gi][0], pb = gl2[gi][1];
    int p0 = pa < pb ? pa : pb, p1 = pa < pb ? pb : pa;
    int m0 = (1 << p0) - 1, m1 = (1 << p1) - 1;
    int ia = 1 << pa, ib = 1 << pb;
    {
      int j = tid >> 3, g = tid & 7;
      int idx = ((g & ~m0) << 1) | (g & m0);
      idx = ((idx & ~m1) << 1) | (idx & m1);
      cpx v0 = rho[idx * 32 + j], v1 = rho[(idx | ib) * 32 + j];
      cpx v2 = rho[(idx | ia) * 32 + j], v3 = rho[(idx | ia | ib) * 32 + j];
      gate4(v0, v1, v2, v3, U);
      rho[idx * 32 + j] = v0; rho[(idx | ib) * 32 + j] = v1;
      rho[(idx | ia) * 32 + j] = v2; rho[(idx | ia | ib) * 32 + j] = v3;
    }
    __syncthreads();
    {
      int i = tid >> 3, g = tid & 7;
      int idx = ((g & ~m0) << 1) | (g & m0);
      idx = ((idx & ~m1) << 1) | (idx & m1);
      cpx v0 = rho[i * 32 + idx], v1 = rho[i * 32 + (idx | ib)];
      cpx v2 = rho[i * 32 + (idx | ia)], v3 = rho[i * 32 + (idx | ia | ib)];
      gate4(v0, v1, v2, v3, Uc);
      rho[i * 32 + idx] = v0; rho[i * 32 + (idx | ib)] = v1;
      rho[i * 32 + (idx | ia)] = v2; rho[i * 32 + (idx | ia | ib)] = v3;
    }
    __syncthreads();
  }
  if (tid < 64) {
    int u = tid >> 3, v = tid & 7;
    cpx acc = mkc(0.f, 0.f);
#pragma unroll
    for (int s = 0; s < 4; s++) {
      int iu = ((s >> 1) << 4) | ((u >> 2) << 3) | ((s & 1) << 2) | (((u >> 1) & 1) << 1) | (u & 1);
      int iv = ((s >> 1) << 4) | ((v >> 2) << 3) | ((s & 1) << 2) | (((v >> 1) & 1) << 1) | (v & 1);
      cpx x = rho[iu * 32 + iv];
      acc.x += x.x; acc.y += x.y;
    }
    r3s[u * 8 + v] = acc;
  }
  __syncthreads();

#pragma unroll
  for (int k = 0; k < 16; k++) { U[k] = Umat[48 + k]; Uc[k] = mkc(U[k].x, -U[k].y); }
  const int gl3[2][2] = {{2,1},{1,0}};
#pragma unroll
  for (int gi = 0; gi < 2; gi++) {
    int pa = gl3[gi][0], pb = gl3[gi][1];
    int p0 = pa < pb ? pa : pb, p1 = pa < pb ? pb : pa;
    int m0 = (1 << p0) - 1, m1 = (1 << p1) - 1;
    int ia = 1 << pa, ib = 1 << pb;
    if (tid < 16) {
      int j = tid >> 1, g = tid & 1;
      int idx = ((g & ~m0) << 1) | (g & m0);
      idx = ((idx & ~m1) << 1) | (idx & m1);
      cpx v0 = r3s[idx * 8 + j], v1 = r3s[(idx | ib) * 8 + j];
      cpx v2 = r3s[(idx | ia) * 8 + j], v3 = r3s[(idx | ia | ib) * 8 + j];
      gate4(v0, v1, v2, v3, U);
      r3s[idx * 8 + j] = v0; r3s[(idx | ib) * 8 + j] = v1;
      r3s[(idx | ia) * 8 + j] = v2; r3s[(idx | ia | ib) * 8 + j] = v3;
    }
    __syncthreads();
    if (tid < 16) {
      int i = tid >> 1, g = tid & 1;
      int idx = ((g & ~m0) << 1) | (g & m0);
      idx = ((idx & ~m1) << 1) | (idx & m1);
      cpx v0 = r3s[i * 8 + idx], v1 = r3s[i * 8 + (idx | ib)];
      cpx v2 = r3s[i * 8 + (idx | ia)], v3 = r3s[i * 8 + (idx | ia | ib)];
      gate4(v0, v1, v2, v3, Uc);
      r3s[i * 8 + idx] = v0; r3s[i * 8 + (idx | ib)] = v1;
      r3s[i * 8 + (idx | ia)] = v2; r3s[i * 8 + (idx | ia | ib)] = v3;
    }
    __syncthreads();
  }
  if (tid < 16) {
    int u = tid >> 2, v = tid & 3;
    cpx acc = mkc(0.f, 0.f);
#pragma unroll
    for (int s = 0; s < 2; s++) {
      cpx x = r3s[((s << 2) | u) * 8 + ((s << 2) | v)];
      acc.x += x.x; acc.y += x.y;
    }
    r4s[u * 4 + v] = acc;
  }
  __syncthreads();

#pragma unroll
  for (int k = 0; k < 16; k++) { U[k] = Umat[64 + k]; Uc[k] = mkc(U[k].x, -U[k].y); }
  if (tid < 4) {
    int j = tid;
    cpx v0 = r4s[0 * 4 + j], v1 = r4s[1 * 4 + j], v2 = r4s[2 * 4 + j], v3 = r4s[3 * 4 + j];
    gate4(v0, v1, v2, v3, U);
    r4s[0 * 4 + j] = v0; r4s[1 * 4 + j] = v1; r4s[2 * 4 + j] = v2; r4s[3 * 4 + j] = v3;
  }
  __syncthreads();
  if (tid < 4) {
    int i = tid;
    cpx v0 = r4s[i * 4 + 0], v1 = r4s[i * 4 + 1], v2 = r4s[i * 4 + 2], v3 = r4s[i * 4 + 3];
    gate4(v0, v1, v2, v3, Uc);
    r4s[i * 4 + 0] = v0; r4s[i * 4 + 1] = v1; r4s[i * 4 + 2] = v2; r4s[i * 4 + 3] = v3;
  }
  __syncthreads();
  if (tid == 0) out[b] = r4s[0].x + r4s[10].x;
}

// ---------------------------------------------------------------------------
extern "C" void kernel_launch(void* const* d_in, const int* in_sizes, int n_in,
                              void* d_out, int out_size, void* d_ws, size_t ws_size,
                              hipStream_t stream) {
  const float* psi_re = (const float*)d_in[0];
  const float* psi_im = (const float*)d_in[1];
  const float* H_re = (const float*)d_in[2];
  const float* H_im = (const float*)d_in[3];
  float* out = (float*)d_out;

  char* ws = (char*)d_ws;
  cpx* Umat = (cpx*)ws;                                       // 80 cpx
  cpx* state = (cpx*)(ws + 4096);                             // 32 MB (layout F)
  float4* partial = (float4*)(ws + 4096 + ((size_t)1 << 25)); // 4 MB

  const size_t LDS_L0 = 8704 * sizeof(cpx);          // padded 8192 = 69632 B
  const size_t LDS_POOL = 8 * T_STR * sizeof(cpx);   // 9224 cpx = 73792 B

  hipLaunchKernelGGL(compute_U, dim3(1), dim3(128), 0, stream, H_re, H_im, Umat);
  hipLaunchKernelGGL(l0_pass1, dim3(512), dim3(1024), LDS_L0, stream,
                     psi_re, psi_im, (const cpx*)Umat, state);
  hipLaunchKernelGGL(l0_pass2, dim3(512), dim3(1024), LDS_L0, stream,
                     (const cpx*)Umat, state);
  hipLaunchKernelGGL(pool_l1, dim3(512), dim3(512), LDS_POOL, stream,
                     (const cpx*)Umat, (const cpx*)state, partial);
  hipLaunchKernelGGL(finish, dim3(4), dim3(256), 0, stream,
                     (const cpx*)Umat, (const float4*)partial, out);
}

// Round 8
// 171.968 us; speedup vs baseline: 1.0641x; 1.0228x over previous
//
#include <hip/hip_runtime.h>
#include <math.h>

// ---------------------------------------------------------------------------
// QCNN forward. Inter-kernel state uses layout F (per batch, 20 bits):
//   F0=a0(u0) F1=a1(t0) F2=a2(s0) F3=a3(t1) F4=a12(u3) F5=a16(u4) F6=a14(s3)
//   F7=a18(s4) F8=a4(u1) F9=a8(u2) F10=a6(s1) F11=a10(s2) F12=a5(t2)
//   F13..19 = thi
// R7 post-mortem: VALU idle 79% AND HBM idle 88% in pass kernels; grid ==
// residency (512 blocks = 2/CU) -> all blocks phase-lockstep; load/gates/store
// never overlap. THIS ROUND: pass1/pass2 = 256 blocks x 1024 thr, 2 tiles per
// block with rolling register prefetch (tile1 loads issued under tile0 gates,
// tile0 store drains under tile1 gates). Named A/B reg buffers, unrolled
// (no runtime-indexed arrays -> no scratch). Gate math verbatim R7.
// pool: R6 known-good (T=1153/S=36 bank-floor; non-atomic partials — ws
// atomics write through to HBM, R2). finish: R6. compute_U separate (SGPR U).
// Complex math on <2 x float> ext-vectors -> v_pk_fma_f32.
// ---------------------------------------------------------------------------

typedef float cpx __attribute__((ext_vector_type(2)));

__device__ __forceinline__ cpx mkc(float x, float y) { cpx r; r.x = x; r.y = y; return r; }

__device__ __forceinline__ cpx cmul(cpx a, cpx b) {
  cpx r = a.xx * b;
  return __builtin_elementwise_fma(mkc(-a.y, a.y), b.yx, r);
}
__device__ __forceinline__ cpx cmadd(cpx acc, cpx a, cpx b) {
  acc = __builtin_elementwise_fma(a.xx, b, acc);
  return __builtin_elementwise_fma(mkc(-a.y, a.y), b.yx, acc);
}
// acc += a * conj(b)
__device__ __forceinline__ cpx cmaddc(cpx acc, cpx a, cpx b) {
  acc = __builtin_elementwise_fma(a.xx, mkc(b.x, -b.y), acc);
  return __builtin_elementwise_fma(a.yy, b.yx, acc);
}

__device__ __forceinline__ int pad(int e) { return e + (e >> 4); }
__device__ __forceinline__ int ins(int x, int p) {
  return ((x >> p) << (p + 1)) | (x & ((1 << p) - 1));
}

#define S_STR 36
#define T_STR 1153

__device__ __forceinline__ void gate4(cpx& v0, cpx& v1, cpx& v2, cpx& v3,
                                      const cpx (&U)[16]) {
  cpx n0 = cmul(U[0], v0);  n0 = cmadd(n0, U[1], v1);  n0 = cmadd(n0, U[2], v2);  n0 = cmadd(n0, U[3], v3);
  cpx n1 = cmul(U[4], v0);  n1 = cmadd(n1, U[5], v1);  n1 = cmadd(n1, U[6], v2);  n1 = cmadd(n1, U[7], v3);
  cpx n2 = cmul(U[8], v0);  n2 = cmadd(n2, U[9], v1);  n2 = cmadd(n2, U[10], v2); n2 = cmadd(n2, U[11], v3);
  cpx n3 = cmul(U[12], v0); n3 = cmadd(n3, U[13], v1); n3 = cmadd(n3, U[14], v2); n3 = cmadd(n3, U[15], v3);
  v0 = n0; v1 = n1; v2 = n2; v3 = n3;
}

template <int NG>
__device__ __forceinline__ void gate16n(cpx (&v)[16], const cpx (&U)[16]) {
#pragma unroll
  for (int g = 0; g < 4; g++)
    gate4(v[g * 4 + 0], v[g * 4 + 1], v[g * 4 + 2], v[g * 4 + 3], U);
#pragma unroll
  for (int lo = 0; lo < 4; lo++)
    gate4(v[lo], v[lo + 4], v[lo + 8], v[lo + 12], U);
  if (NG == 3) {
#pragma unroll
    for (int b3 = 0; b3 < 2; b3++)
#pragma unroll
      for (int b0 = 0; b0 < 2; b0++) {
        int j = b3 * 8 + b0;
        gate4(v[j], v[j + 2], v[j + 4], v[j + 6], U);
      }
  }
}

// single 2-qubit gate (bits pa,pb) over padded 2^13 tile, 1024 thr
__device__ __forceinline__ void apply_gate_2it(cpx* t, const cpx (&U)[16],
                                               int pa, int pb, int tid) {
  int p0 = pa < pb ? pa : pb;
  int p1 = pa < pb ? pb : pa;
  int m0 = (1 << p0) - 1, m1 = (1 << p1) - 1;
  int ia = 1 << pa, ib = 1 << pb;
#pragma unroll
  for (int g = tid; g < 2048; g += 1024) {
    int idx = ((g & ~m0) << 1) | (g & m0);
    idx = ((idx & ~m1) << 1) | (idx & m1);
    int e0 = pad(idx), e1 = pad(idx | ib), e2 = pad(idx | ia), e3 = pad(idx | ia | ib);
    cpx v0 = t[e0], v1 = t[e1], v2 = t[e2], v3 = t[e3];
    gate4(v0, v1, v2, v3, U);
    t[e0] = v0; t[e1] = v1; t[e2] = v2; t[e3] = v3;
  }
}

// 8-cpx register phase for 1024 threads over padded 2^13 tile.
// q0<q1<q2 sorted bits; gates: EVEN (o2,o1) first, then ODD (o1,o0).
__device__ __forceinline__ void phase3_eo(cpx* t, const cpx (&U)[16],
                                          int q0, int q1, int q2,
                                          int o0, int o1, int o2, int tid) {
  int idx = ins(ins(ins(tid, q0), q1), q2);
  cpx v[8];
#pragma unroll
  for (int j = 0; j < 8; j++) {
    int off = ((j & 1) ? o0 : 0) + ((j & 2) ? o1 : 0) + ((j & 4) ? o2 : 0);
    v[j] = t[pad(idx + off)];
  }
  gate4(v[0], v[2], v[4], v[6], U);  // (o2,o1), o0=0
  gate4(v[1], v[3], v[5], v[7], U);  // (o2,o1), o0=1
  gate4(v[0], v[1], v[2], v[3], U);  // (o1,o0), o2=0
  gate4(v[4], v[5], v[6], v[7], U);  // (o1,o0), o2=1
#pragma unroll
  for (int j = 0; j < 8; j++) {
    int off = ((j & 1) ? o0 : 0) + ((j & 2) ? o1 : 0) + ((j & 4) ? o2 : 0);
    t[pad(idx + off)] = v[j];
  }
}

// pool register phase (stride-S_STR LDS), 512 threads
template <int NG>
__device__ __forceinline__ void phase4_pool(cpx* w, const cpx (&U)[16],
                                            int a_lo, int a_hi, int c_lo, int c_hi,
                                            int o0, int o1, int o2, int o3, int tid) {
  int uu = tid & 7, ss = (tid >> 3) & 7, t_lo = tid >> 6;
  int u = ins(ins(uu, a_lo), a_hi);
  int s = ins(ins(ss, c_lo), c_hi);
  int base = t_lo * T_STR + s * S_STR + u;
  cpx v[16];
#pragma unroll
  for (int j = 0; j < 16; j++) {
    int off = ((j & 1) ? o0 : 0) + ((j & 2) ? o1 : 0) + ((j & 4) ? o2 : 0) + ((j & 8) ? o3 : 0);
    v[j] = w[base + off];
  }
  gate16n<NG>(v, U);
#pragma unroll
  for (int j = 0; j < 16; j++) {
    int off = ((j & 1) ? o0 : 0) + ((j & 2) ? o1 : 0) + ((j & 4) ? o2 : 0) + ((j & 8) ? o3 : 0);
    w[base + off] = v[j];
  }
}

__device__ __forceinline__ void pool_p3(cpx* w, const cpx (&U)[16], int tid) {
#pragma unroll
  for (int it = 0; it < 2; it++) {
    int h = tid + it * 512;
    int t_lo = h & 7, ss = (h >> 3) & 15, uu = (h >> 7) & 7;
    int base = t_lo * T_STR + (ss << 1) * S_STR + (uu << 2);
    cpx v[8];
    v[0] = w[base];          v[1] = w[base + 1];
    v[4] = w[base + 2];      v[5] = w[base + 3];
    v[2] = w[base + S_STR];      v[3] = w[base + S_STR + 1];
    v[6] = w[base + S_STR + 2];  v[7] = w[base + S_STR + 3];
    gate4(v[0], v[1], v[2], v[3], U);
    gate4(v[4], v[5], v[6], v[7], U);
    gate4(v[0], v[2], v[4], v[6], U);
    gate4(v[1], v[3], v[5], v[7], U);
    w[base] = v[0];          w[base + 1] = v[1];
    w[base + 2] = v[4];      w[base + 3] = v[5];
    w[base + S_STR] = v[2];      w[base + S_STR + 1] = v[3];
    w[base + S_STR + 2] = v[6];  w[base + S_STR + 3] = v[7];
  }
}

// 16-lane expm(A - A^H) in fp64, width-16 shuffles.
__device__ __forceinline__ cpx expm16(const float* __restrict__ Hre,
                                      const float* __restrict__ Him,
                                      int l, int l16) {
  int r = l16 >> 2, c = l16 & 3;
  double tr = (double)Hre[l * 16 + r * 4 + c] - (double)Hre[l * 16 + c * 4 + r];
  double ti = (double)Him[l * 16 + r * 4 + c] + (double)Him[l * 16 + c * 4 + r];
  double a = sqrt(tr * tr + ti * ti);
  a += __shfl_xor(a, 1, 16);
  a += __shfl_xor(a, 2, 16);
  double nrm = fmax(a, __shfl_xor(a, 4, 16));
  nrm = fmax(nrm, __shfl_xor(nrm, 8, 16));
  int s = 0;
  while (nrm > 0.25 && s < 60) { nrm *= 0.5; s++; }
  double sc = ldexp(1.0, -s);
  tr *= sc; ti *= sc;
  double id = (r == c) ? 1.0 : 0.0;
  double er = id, ei = 0.0, pr = id, pi = 0.0;
  for (int k = 1; k <= 16; k++) {
    double qr = 0.0, qi = 0.0;
#pragma unroll
    for (int m = 0; m < 4; m++) {
      double pmr = __shfl(pr, r * 4 + m, 16);
      double pmi = __shfl(pi, r * 4 + m, 16);
      double tmr = __shfl(tr, m * 4 + c, 16);
      double tmi = __shfl(ti, m * 4 + c, 16);
      qr = fma(pmr, tmr, fma(-pmi, tmi, qr));
      qi = fma(pmr, tmi, fma(pmi, tmr, qi));
    }
    double inv = 1.0 / (double)k;
    pr = qr * inv; pi = qi * inv;
    er += pr; ei += pi;
  }
  for (int it = 0; it < s; it++) {
    double qr = 0.0, qi = 0.0;
#pragma unroll
    for (int m = 0; m < 4; m++) {
      double amr = __shfl(er, r * 4 + m, 16);
      double ami = __shfl(ei, r * 4 + m, 16);
      double bmr = __shfl(er, m * 4 + c, 16);
      double bmi = __shfl(ei, m * 4 + c, 16);
      qr = fma(amr, bmr, fma(-ami, bmi, qr));
      qi = fma(amr, bmi, fma(ami, bmr, qi));
    }
    er = qr; ei = qi;
  }
  return mkc((float)er, (float)ei);
}

// ---------------------------------------------------------------------------
// Kernel A: compute all 5 layer unitaries into Umat. 1 block, 128 threads.
// ---------------------------------------------------------------------------
__global__ __launch_bounds__(128) void compute_U(const float* __restrict__ Hre,
                                                 const float* __restrict__ Him,
                                                 cpx* __restrict__ Umat) {
  int tid = threadIdx.x;
  if (tid < 80) {
    int layer = tid >> 4, l16 = tid & 15;
    Umat[layer * 16 + l16] = expm16(Hre, Him, layer, l16);
  }
}

// pass1 gate phases over the LDS tile (R7-verified sequence, 1024 thr)
__device__ __forceinline__ void p1_phases(cpx* tile, const cpx (&U)[16], int tid) {
  apply_gate_2it(tile, U, 1, 0, tid);                 __syncthreads(); // (a1,a0)
  phase3_eo(tile, U, 1, 2, 3, 2, 4, 8, tid);          __syncthreads(); // (a3,a2),(a2,a1)
  phase3_eo(tile, U, 3, 4, 5, 8, 16, 32, tid);        __syncthreads(); // (a5,a4),(a4,a3)
  phase3_eo(tile, U, 5, 6, 7, 32, 64, 128, tid);      __syncthreads(); // (a7,a6),(a6,a5)
  phase3_eo(tile, U, 7, 8, 9, 128, 256, 512, tid);    __syncthreads(); // (a9,a8),(a8,a7)
  phase3_eo(tile, U, 9, 10, 11, 512, 1024, 2048, tid);__syncthreads(); // (a11,a10),(a10,a9)
}

// pass1 permuted store: LDS -> layout F (R3-verified maps)
__device__ __forceinline__ void p1_store(cpx* tile, cpx* __restrict__ state,
                                         int b, int hi, int tid) {
  int hifix = ((hi & 1) << 16) | (((hi >> 1) & 1) << 6) | (((hi >> 2) & 1) << 17)
            | (((hi >> 3) & 1) << 5) | (((hi >> 4) & 1) << 18) | (((hi >> 5) & 1) << 7)
            | (((hi >> 6) & 1) << 19);
  size_t dbase = ((size_t)b << 20) | (unsigned)hifix;
  cpx x[8];
#pragma unroll
  for (int k = 0; k < 2; k++) {
    int src = pad((tid + (k << 10)) << 2);
    x[4 * k + 0] = tile[src];     x[4 * k + 1] = tile[src + 1];
    x[4 * k + 2] = tile[src + 2]; x[4 * k + 3] = tile[src + 3];
  }
#pragma unroll
  for (int k = 0; k < 2; k++) {
    int le = tid + (k << 10);
    int d = ((le & 1) << 2) | (((le >> 1) & 1) << 3) | (((le >> 2) & 1) << 8)
          | (((le >> 3) & 1) << 12) | (((le >> 4) & 1) << 10) | (((le >> 5) & 1) << 13)
          | (((le >> 6) & 1) << 9) | (((le >> 7) & 1) << 14) | (((le >> 8) & 1) << 11)
          | (((le >> 9) & 1) << 15) | (((le >> 10) & 1) << 4);
    float4* dst = (float4*)&state[dbase + d];
    dst[0] = make_float4(x[4 * k].x, x[4 * k].y, x[4 * k + 1].x, x[4 * k + 1].y);
    dst[1] = make_float4(x[4 * k + 2].x, x[4 * k + 2].y, x[4 * k + 3].x, x[4 * k + 3].y);
  }
}

// ---------------------------------------------------------------------------
// Kernel B: layer-0 pass 1. 256 blocks x 1024 thr, 2 tiles/block, rolling
// prefetch: tile1 loads issue under tile0 gate phases; tile0 store drains
// under tile1 gates. Tiles: t in {bid, bid+256}; b=t>>7, hi=t&127.
// ---------------------------------------------------------------------------
__global__ __launch_bounds__(1024, 4) void l0_pass1(const float* __restrict__ pre,
                                                    const float* __restrict__ pim,
                                                    const cpx* __restrict__ Umat,
                                                    cpx* __restrict__ state) {
  extern __shared__ cpx tile[];
  int tid = threadIdx.x;
  int bid = blockIdx.x;
  int t0 = bid, t1 = bid + 256;
  size_t baseA = ((size_t)(t0 >> 7) << 20) | ((size_t)(t0 & 127) << 13);
  size_t baseB = ((size_t)(t1 >> 7) << 20) | ((size_t)(t1 & 127) << 13);
  cpx U[16];
#pragma unroll
  for (int k = 0; k < 16; k++) U[k] = Umat[k];
  // ---- load tile0 into regs A ----
  float4 reA0, reA1, imA0, imA1;
  {
    int e0 = tid << 2, e1 = (tid + 1024) << 2;
    reA0 = *(const float4*)&pre[baseA + e0];
    reA1 = *(const float4*)&pre[baseA + e1];
    imA0 = *(const float4*)&pim[baseA + e0];
    imA1 = *(const float4*)&pim[baseA + e1];
  }
  // ---- iter 0: stage A, prefetch B, compute, store ----
  {
    int e0 = tid << 2, e1 = (tid + 1024) << 2;
    int d0 = pad(e0), d1 = pad(e1);
    tile[d0]     = mkc(reA0.x, imA0.x);
    tile[d0 + 1] = mkc(reA0.y, imA0.y);
    tile[d0 + 2] = mkc(reA0.z, imA0.z);
    tile[d0 + 3] = mkc(reA0.w, imA0.w);
    tile[d1]     = mkc(reA1.x, imA1.x);
    tile[d1 + 1] = mkc(reA1.y, imA1.y);
    tile[d1 + 2] = mkc(reA1.z, imA1.z);
    tile[d1 + 3] = mkc(reA1.w, imA1.w);
  }
  __syncthreads();
  // prefetch tile1 (waitcnt deferred to first use in iter 1)
  float4 reB0, reB1, imB0, imB1;
  {
    int e0 = tid << 2, e1 = (tid + 1024) << 2;
    reB0 = *(const float4*)&pre[baseB + e0];
    reB1 = *(const float4*)&pre[baseB + e1];
    imB0 = *(const float4*)&pim[baseB + e0];
    imB1 = *(const float4*)&pim[baseB + e1];
  }
  p1_phases(tile, U, tid);
  p1_store(tile, state, t0 >> 7, t0 & 127, tid);
  __syncthreads();  // LDS reads done; safe to overwrite
  // ---- iter 1: stage B, compute, store ----
  {
    int e0 = tid << 2, e1 = (tid + 1024) << 2;
    int d0 = pad(e0), d1 = pad(e1);
    tile[d0]     = mkc(reB0.x, imB0.x);
    tile[d0 + 1] = mkc(reB0.y, imB0.y);
    tile[d0 + 2] = mkc(reB0.z, imB0.z);
    tile[d0 + 3] = mkc(reB0.w, imB0.w);
    tile[d1]     = mkc(reB1.x, imB1.x);
    tile[d1 + 1] = mkc(reB1.y, imB1.y);
    tile[d1 + 2] = mkc(reB1.z, imB1.z);
    tile[d1 + 3] = mkc(reB1.w, imB1.w);
  }
  __syncthreads();
  p1_phases(tile, U, tid);
  p1_store(tile, state, t1 >> 7, t1 & 127, tid);
}

// pass2 gate phases (R7-verified sequence, 1024 thr)
__device__ __forceinline__ void p2_phases(cpx* tile, const cpx (&U)[16], int tid) {
  phase3_eo(tile, U, 4, 8, 9, 256, 16, 512, tid);     __syncthreads(); // E1,O1
  phase3_eo(tile, U, 6, 9, 10, 512, 64, 1024, tid);   __syncthreads(); // E2,O2
  phase3_eo(tile, U, 5, 10, 11, 1024, 32, 2048, tid); __syncthreads(); // E3,O3
  phase3_eo(tile, U, 7, 11, 12, 2048, 128, 4096, tid);__syncthreads(); // E4,O4
  apply_gate_2it(tile, U, 0, 12, tid);                __syncthreads(); // W
}

// ---------------------------------------------------------------------------
// Kernel C: layer-0 pass 2 in layout F. 256 blocks x 1024 thr, 2 tiles/block
// with rolling prefetch. Tiles: t in {bid, bid+256}; b=t>>7, mid=t&127.
// ---------------------------------------------------------------------------
__global__ __launch_bounds__(1024, 4) void l0_pass2(const cpx* __restrict__ Umat,
                                                    cpx* __restrict__ state) {
  extern __shared__ cpx tile[];
  int tid = threadIdx.x;
  int bid = blockIdx.x;
  int t0 = bid, t1 = bid + 256;
  size_t baseA = ((size_t)(t0 >> 7) << 20) | ((size_t)(t0 & 127) << 8);
  size_t baseB = ((size_t)(t1 >> 7) << 20) | ((size_t)(t1 & 127) << 8);
  cpx U[16];
#pragma unroll
  for (int k = 0; k < 16; k++) U[k] = Umat[k];
  // load tile0
  float4 vA[4];
#pragma unroll
  for (int k = 0; k < 4; k++) {
    int f = tid + (k << 10);
    vA[k] = *(const float4*)&state[baseA + ((size_t)(f >> 7) << 15) + ((size_t)(f & 127) << 1)];
  }
  // iter 0
#pragma unroll
  for (int k = 0; k < 4; k++) {
    int f = tid + (k << 10);
    int d = pad((f >> 7) * 256 + (f & 127) * 2);
    tile[d] = mkc(vA[k].x, vA[k].y);
    tile[d + 1] = mkc(vA[k].z, vA[k].w);
  }
  __syncthreads();
  float4 vB[4];  // prefetch tile1
#pragma unroll
  for (int k = 0; k < 4; k++) {
    int f = tid + (k << 10);
    vB[k] = *(const float4*)&state[baseB + ((size_t)(f >> 7) << 15) + ((size_t)(f & 127) << 1)];
  }
  p2_phases(tile, U, tid);
  {
    cpx y[8];
#pragma unroll
    for (int k = 0; k < 4; k++) {
      int f = tid + (k << 10);
      int d = pad((f >> 7) * 256 + (f & 127) * 2);
      y[2 * k] = tile[d];
      y[2 * k + 1] = tile[d + 1];
    }
#pragma unroll
    for (int k = 0; k < 4; k++) {
      int f = tid + (k << 10);
      size_t a = baseA + ((size_t)(f >> 7) << 15) + ((size_t)(f & 127) << 1);
      *(float4*)&state[a] = make_float4(y[2 * k].x, y[2 * k].y, y[2 * k + 1].x, y[2 * k + 1].y);
    }
  }
  __syncthreads();
  // iter 1
#pragma unroll
  for (int k = 0; k < 4; k++) {
    int f = tid + (k << 10);
    int d = pad((f >> 7) * 256 + (f & 127) * 2);
    tile[d] = mkc(vB[k].x, vB[k].y);
    tile[d + 1] = mkc(vB[k].z, vB[k].w);
  }
  __syncthreads();
  p2_phases(tile, U, tid);
  {
    cpx y[8];
#pragma unroll
    for (int k = 0; k < 4; k++) {
      int f = tid + (k << 10);
      int d = pad((f >> 7) * 256 + (f & 127) * 2);
      y[2 * k] = tile[d];
      y[2 * k + 1] = tile[d + 1];
    }
#pragma unroll
    for (int k = 0; k < 4; k++) {
      int f = tid + (k << 10);
      size_t a = baseB + ((size_t)(f >> 7) << 15) + ((size_t)(f & 127) << 1);
      *(float4*)&state[a] = make_float4(y[2 * k].x, y[2 * k].y, y[2 * k + 1].x, y[2 * k + 1].y);
    }
  }
}

// ---------------------------------------------------------------------------
// Kernel D: pool0 + layer1 gates + pool1 (R6 known-good, 512 blk x 512 thr).
// ---------------------------------------------------------------------------
__global__ __launch_bounds__(512, 4) void pool_l1(const cpx* __restrict__ Umat,
                                                  const cpx* __restrict__ state,
                                                  float4* __restrict__ partial) {
  extern __shared__ cpx w[];  // 8*T_STR = 9224 cpx
  int tid = threadIdx.x;
  int bid = blockIdx.x;
  int b = bid >> 7, thi = bid & 127;
  size_t base = ((size_t)b << 20) | ((size_t)thi << 13);
  cpx U[16];
#pragma unroll
  for (int k = 0; k < 16; k++) U[k] = Umat[16 + k];
  {
    float4 v[8];
#pragma unroll
    for (int k = 0; k < 8; k++) {
      int e = (tid + (k << 9)) << 1;
      v[k] = *(const float4*)&state[base + e];
    }
#pragma unroll
    for (int k = 0; k < 8; k++) {
      int e = (tid + (k << 9)) << 1;
      int u = (((e >> 8) & 1) << 1) | (((e >> 9) & 1) << 2) | (((e >> 4) & 1) << 3) | (((e >> 5) & 1) << 4);
      int s = ((e >> 2) & 1) | (((e >> 10) & 1) << 1) | (((e >> 11) & 1) << 2)
            | (((e >> 6) & 1) << 3) | (((e >> 7) & 1) << 4);
      int t = ((e >> 1) & 1) | (((e >> 3) & 1) << 1) | (((e >> 12) & 1) << 2);
      int c = t * T_STR + s * S_STR + u;
      w[c] = mkc(v[k].x, v[k].y);
      w[c + 1] = mkc(v[k].z, v[k].w);
    }
  }
  __syncthreads();
  phase4_pool<3>(w, U, 3, 4, 3, 4, 8, 8 * S_STR, 16, 16 * S_STR, tid); __syncthreads(); // {7,6},{9,8},{8,7}
  phase4_pool<3>(w, U, 1, 2, 1, 2, 2, 2 * S_STR, 4, 4 * S_STR, tid);   __syncthreads(); // {3,2},{5,4},{4,3}
  pool_p3(w, U, tid);                                                  __syncthreads(); // {1,0},{2,1}
  phase4_pool<2>(w, U, 0, 3, 2, 4, 4 * S_STR, 8, 16 * S_STR, 1, tid);  __syncthreads(); // {6,5},{0,9}
  int wv = tid >> 6, lane = tid & 63;
  int u0 = (lane >> 3) << 2, v0 = (lane & 7) << 2;
  cpx acc[4][4];
#pragma unroll
  for (int i = 0; i < 4; i++)
#pragma unroll
    for (int j = 0; j < 4; j++) acc[i][j] = mkc(0.f, 0.f);
  {
    int tb = wv * T_STR;
#pragma unroll 4
    for (int s = 0; s < 32; s++) {
      int row = tb + s * S_STR;
      cpx x[4], y[4];
#pragma unroll
      for (int i = 0; i < 4; i++) { x[i] = w[row + u0 + i]; y[i] = w[row + v0 + i]; }
#pragma unroll
      for (int i = 0; i < 4; i++)
#pragma unroll
        for (int j = 0; j < 4; j++) acc[i][j] = cmaddc(acc[i][j], x[i], y[j]);
    }
  }
  __syncthreads();  // w dead; reuse for cross-wave reduce
#pragma unroll
  for (int i = 0; i < 4; i++)
#pragma unroll
    for (int j = 0; j < 4; j++)
      w[wv * 1024 + (u0 + i) * 32 + (v0 + j)] = acc[i][j];
  __syncthreads();
  {
    cpx s0 = mkc(0.f, 0.f), s1 = mkc(0.f, 0.f);
#pragma unroll
    for (int k = 0; k < 8; k++) {
      s0 += w[k * 1024 + 2 * tid];
      s1 += w[k * 1024 + 2 * tid + 1];
    }
    partial[((size_t)bid << 9) | tid] = make_float4(s0.x, s0.y, s1.x, s1.y);
  }
}

// ---------------------------------------------------------------------------
// Kernel F: fold 128 tiles + layers 2..4 (32x32 -> 2x2 dm) + measure.
// ---------------------------------------------------------------------------
__global__ __launch_bounds__(256) void finish(const cpx* __restrict__ Umat,
                                              const float4* __restrict__ accv,
                                              float* __restrict__ out) {
  __shared__ cpx rho[1024];
  __shared__ cpx r3s[64];
  __shared__ cpx r4s[16];
  int tid = threadIdx.x;
  int b = blockIdx.x;
  float4* rf = (float4*)rho;
  for (int f = tid; f < 512; f += 256) {
    float4 acc = make_float4(0.f, 0.f, 0.f, 0.f);
#pragma unroll 8
    for (int h = 0; h < 128; h++) {
      float4 v = accv[(size_t)(b * 128 + h) * 512 + f];
      acc.x += v.x; acc.y += v.y; acc.z += v.z; acc.w += v.w;
    }
    rf[f] = acc;
  }
  __syncthreads();

  cpx U[16], Uc[16];
#pragma unroll
  for (int k = 0; k < 16; k++) { U[k] = Umat[32 + k]; Uc[k] = mkc(U[k].x, -U[k].y); }
  const int gl2[4][2] = {{4,3},{2,1},{3,2},{1,0}};
#pragma unroll
  for (int gi = 0; gi < 4; gi++) {
    int pa = gl2[gi][0], pb = gl2[gi][1];
    int p0 = pa < pb ? pa : pb, p1 = pa < pb ? pb : pa;
    int m0 = (1 << p0) - 1, m1 = (1 << p1) - 1;
    int ia = 1 << pa, ib = 1 << pb;
    {
      int j = tid >> 3, g = tid & 7;
      int idx = ((g & ~m0) << 1) | (g & m0);
      idx = ((idx & ~m1) << 1) | (idx & m1);
      cpx v0 = rho[idx * 32 + j], v1 = rho[(idx | ib) * 32 + j];
      cpx v2 = rho[(idx | ia) * 32 + j], v3 = rho[(idx | ia | ib) * 32 + j];
      gate4(v0, v1, v2, v3, U);
      rho[idx * 32 + j] = v0; rho[(idx | ib) * 32 + j] = v1;
      rho[(idx | ia) * 32 + j] = v2; rho[(idx | ia | ib) * 32 + j] = v3;
    }
    __syncthreads();
    {
      int i = tid >> 3, g = tid & 7;
      int idx = ((g & ~m0) << 1) | (g & m0);
      idx = ((idx & ~m1) << 1) | (idx & m1);
      cpx v0 = rho[i * 32 + idx], v1 = rho[i * 32 + (idx | ib)];
      cpx v2 = rho[i * 32 + (idx | ia)], v3 = rho[i * 32 + (idx | ia | ib)];
      gate4(v0, v1, v2, v3, Uc);
      rho[i * 32 + idx] = v0; rho[i * 32 + (idx | ib)] = v1;
      rho[i * 32 + (idx | ia)] = v2; rho[i * 32 + (idx | ia | ib)] = v3;
    }
    __syncthreads();
  }
  if (tid < 64) {
    int u = tid >> 3, v = tid & 7;
    cpx acc = mkc(0.f, 0.f);
#pragma unroll
    for (int s = 0; s < 4; s++) {
      int iu = ((s >> 1) << 4) | ((u >> 2) << 3) | ((s & 1) << 2) | (((u >> 1) & 1) << 1) | (u & 1);
      int iv = ((s >> 1) << 4) | ((v >> 2) << 3) | ((s & 1) << 2) | (((v >> 1) & 1) << 1) | (v & 1);
      cpx x = rho[iu * 32 + iv];
      acc.x += x.x; acc.y += x.y;
    }
    r3s[u * 8 + v] = acc;
  }
  __syncthreads();

#pragma unroll
  for (int k = 0; k < 16; k++) { U[k] = Umat[48 + k]; Uc[k] = mkc(U[k].x, -U[k].y); }
  const int gl3[2][2] = {{2,1},{1,0}};
#pragma unroll
  for (int gi = 0; gi < 2; gi++) {
    int pa = gl3[gi][0], pb = gl3[gi][1];
    int p0 = pa < pb ? pa : pb, p1 = pa < pb ? pb : pa;
    int m0 = (1 << p0) - 1, m1 = (1 << p1) - 1;
    int ia = 1 << pa, ib = 1 << pb;
    if (tid < 16) {
      int j = tid >> 1, g = tid & 1;
      int idx = ((g & ~m0) << 1) | (g & m0);
      idx = ((idx & ~m1) << 1) | (idx & m1);
      cpx v0 = r3s[idx * 8 + j], v1 = r3s[(idx | ib) * 8 + j];
      cpx v2 = r3s[(idx | ia) * 8 + j], v3 = r3s[(idx | ia | ib) * 8 + j];
      gate4(v0, v1, v2, v3, U);
      r3s[idx * 8 + j] = v0; r3s[(idx | ib) * 8 + j] = v1;
      r3s[(idx | ia) * 8 + j] = v2; r3s[(idx | ia | ib) * 8 + j] = v3;
    }
    __syncthreads();
    if (tid < 16) {
      int i = tid >> 1, g = tid & 1;
      int idx = ((g & ~m0) << 1) | (g & m0);
      idx = ((idx & ~m1) << 1) | (idx & m1);
      cpx v0 = r3s[i * 8 + idx], v1 = r3s[i * 8 + (idx | ib)];
      cpx v2 = r3s[i * 8 + (idx | ia)], v3 = r3s[i * 8 + (idx | ia | ib)];
      gate4(v0, v1, v2, v3, Uc);
      r3s[i * 8 + idx] = v0; r3s[i * 8 + (idx | ib)] = v1;
      r3s[i * 8 + (idx | ia)] = v2; r3s[i * 8 + (idx | ia | ib)] = v3;
    }
    __syncthreads();
  }
  if (tid < 16) {
    int u = tid >> 2, v = tid & 3;
    cpx acc = mkc(0.f, 0.f);
#pragma unroll
    for (int s = 0; s < 2; s++) {
      cpx x = r3s[((s << 2) | u) * 8 + ((s << 2) | v)];
      acc.x += x.x; acc.y += x.y;
    }
    r4s[u * 4 + v] = acc;
  }
  __syncthreads();

#pragma unroll
  for (int k = 0; k < 16; k++) { U[k] = Umat[64 + k]; Uc[k] = mkc(U[k].x, -U[k].y); }
  if (tid < 4) {
    int j = tid;
    cpx v0 = r4s[0 * 4 + j], v1 = r4s[1 * 4 + j], v2 = r4s[2 * 4 + j], v3 = r4s[3 * 4 + j];
    gate4(v0, v1, v2, v3, U);
    r4s[0 * 4 + j] = v0; r4s[1 * 4 + j] = v1; r4s[2 * 4 + j] = v2; r4s[3 * 4 + j] = v3;
  }
  __syncthreads();
  if (tid < 4) {
    int i = tid;
    cpx v0 = r4s[i * 4 + 0], v1 = r4s[i * 4 + 1], v2 = r4s[i * 4 + 2], v3 = r4s[i * 4 + 3];
    gate4(v0, v1, v2, v3, Uc);
    r4s[i * 4 + 0] = v0; r4s[i * 4 + 1] = v1; r4s[i * 4 + 2] = v2; r4s[i * 4 + 3] = v3;
  }
  __syncthreads();
  if (tid == 0) out[b] = r4s[0].x + r4s[10].x;
}

// ---------------------------------------------------------------------------
extern "C" void kernel_launch(void* const* d_in, const int* in_sizes, int n_in,
                              void* d_out, int out_size, void* d_ws, size_t ws_size,
                              hipStream_t stream) {
  const float* psi_re = (const float*)d_in[0];
  const float* psi_im = (const float*)d_in[1];
  const float* H_re = (const float*)d_in[2];
  const float* H_im = (const float*)d_in[3];
  float* out = (float*)d_out;

  char* ws = (char*)d_ws;
  cpx* Umat = (cpx*)ws;                                       // 80 cpx
  cpx* state = (cpx*)(ws + 4096);                             // 32 MB (layout F)
  float4* partial = (float4*)(ws + 4096 + ((size_t)1 << 25)); // 4 MB

  const size_t LDS_L0 = 8704 * sizeof(cpx);          // padded 8192 = 69632 B
  const size_t LDS_POOL = 8 * T_STR * sizeof(cpx);   // 9224 cpx = 73792 B

  hipLaunchKernelGGL(compute_U, dim3(1), dim3(128), 0, stream, H_re, H_im, Umat);
  hipLaunchKernelGGL(l0_pass1, dim3(256), dim3(1024), LDS_L0, stream,
                     psi_re, psi_im, (const cpx*)Umat, state);
  hipLaunchKernelGGL(l0_pass2, dim3(256), dim3(1024), LDS_L0, stream,
                     (const cpx*)Umat, state);
  hipLaunchKernelGGL(pool_l1, dim3(512), dim3(512), LDS_POOL, stream,
                     (const cpx*)Umat, (const cpx*)state, partial);
  hipLaunchKernelGGL(finish, dim3(4), dim3(256), 0, stream,
                     (const cpx*)Umat, (const float4*)partial, out);
}